// Round 8
// baseline (831.865 us; speedup 1.0000x reference)
//
#include <hip/hip_runtime.h>
#include <hip/hip_bf16.h>
#include <hip/hip_cooperative_groups.h>

namespace cg = cooperative_groups;

// Problem constants (from reference)
#define NPTS   100000
#define NCENT  50000
#define NEDGE  1600000
#define DF     64      // feature dim
#define DP     3       // pos dim
#define DH     128     // hidden
#define DOUT   128     // out
#define TILE   128     // edges per block-tile
#define NTILES (NEDGE / TILE)   // 12500
#define LDA    104     // A-tile leading dim (ushorts), 96 + 8 pad
#define LDH    136     // H1-tile leading dim (ushorts), 128 + 8 pad
#define LDE    132     // Sf2 edge stride (floats), 128 + 4 pad
#define NCPAD  50176   // NCENT padded to 196*256

typedef __attribute__((ext_vector_type(8))) short short8;
typedef __attribute__((ext_vector_type(4))) float f32x4;

__device__ __forceinline__ unsigned short f2bf(float f) {
  union { __hip_bfloat16 h; unsigned short u; } v;
  v.h = __float2bfloat16(f);
  return v.u;
}

// Order-preserving float->uint encoding: uint compare == float compare.
// key==0 is below every encodable real value -> "-inf / untouched".
__device__ __forceinline__ unsigned encodeKey(float f) {
  unsigned u = __float_as_uint(f);
  return u ^ ((unsigned)((int)u >> 31) | 0x80000000u);
}

__device__ __forceinline__ float decodeKey(unsigned k) {
  if (k == 0u) return 0.0f;  // empty segment -> 0 (torch_scatter convention)
  unsigned u = (k & 0x80000000u) ? (k ^ 0x80000000u) : ~k;
  return __uint_as_float(u);
}

// ONE cooperative kernel: prep -> rank -> scan -> place -> mlp -> decode,
// separated by grid.sync(). All phases grid-stride (any grid >= 256 works).
__global__ void __launch_bounds__(256, 4)
k_all(const float* __restrict__ x, const float* __restrict__ pos,
      const float* __restrict__ pos_c, const int* __restrict__ src,
      const int* __restrict__ dstE, const float* __restrict__ W1,
      const float* __restrict__ b1, const float* __restrict__ W2,
      const float* __restrict__ b2, unsigned* __restrict__ outU,
      unsigned short* __restrict__ xbf, unsigned short* __restrict__ W1f,
      unsigned short* __restrict__ W2f, int* __restrict__ cnt,
      unsigned short* __restrict__ rankA, int* __restrict__ bsum,
      unsigned long long* __restrict__ sdS) {
  cg::grid_group grid = cg::this_grid();
  __shared__ __align__(16) unsigned short buf[TILE * LDH];  // 34816 B
  __shared__ int dstLoc[TILE];
  __shared__ int pre_s;

  const int t = threadIdx.x;
  const int b = blockIdx.x;
  const int tid = b * 256 + t;
  const int gsz = gridDim.x * 256;

  // ================= P0: zero cnt, init outU, cvt x, pack W1/W2 ==========
  if (tid < NCPAD) cnt[tid] = 0;
  for (int i = tid; i < NCENT * DOUT / 4; i += gsz)
    reinterpret_cast<uint4*>(outU)[i] = make_uint4(0u, 0u, 0u, 0u);
  for (int i = tid; i < NPTS * DF / 8; i += gsz) {
    const float4* xr = reinterpret_cast<const float4*>(x);
    float4 v0 = xr[2 * i], v1 = xr[2 * i + 1];
    short8 w;
    w[0] = (short)f2bf(v0.x); w[1] = (short)f2bf(v0.y);
    w[2] = (short)f2bf(v0.z); w[3] = (short)f2bf(v0.w);
    w[4] = (short)f2bf(v1.x); w[5] = (short)f2bf(v1.y);
    w[6] = (short)f2bf(v1.z); w[7] = (short)f2bf(v1.w);
    reinterpret_cast<short8*>(xbf)[i] = w;
  }
  if (tid < 1536) {                     // pack W1 -> bf16 B-frags, K pad to 96
    int lane = tid & 63, g = tid >> 6;
    int nt = g / 3, ks = g % 3;
    int n = nt * 16 + (lane & 15);
    int k0 = ks * 32 + (lane >> 4) * 8;
    short8 v;
    for (int j = 0; j < 8; ++j) {
      int k = k0 + j;
      float f = (k < DF + DP) ? W1[k * DH + n] : 0.0f;
      v[j] = (short)f2bf(f);
    }
    *reinterpret_cast<short8*>(W1f + (size_t)tid * 8) = v;
  } else if (tid >= 2048 && tid < 4096) {  // pack W2 -> bf16 B-frags
    int t2 = tid - 2048;
    int lane = t2 & 63, g = t2 >> 6;
    int nt = g >> 2, ks = g & 3;
    int n = nt * 16 + (lane & 15);
    int k0 = ks * 32 + (lane >> 4) * 8;
    short8 v;
    for (int j = 0; j < 8; ++j) {
      int k = k0 + j;
      v[j] = (short)f2bf(W2[k * DH + n]);
    }
    *reinterpret_cast<short8*>(W2f + (size_t)t2 * 8) = v;
  }
  grid.sync();

  // ================= P1: rank (one returning-atomic pass) ================
  for (int i = tid; i < NEDGE; i += gsz)
    rankA[i] = (unsigned short)atomicAdd(&cnt[dstE[i]], 1);
  grid.sync();

  // ================= P2: per-256-chunk sums ==============================
  int* shi = reinterpret_cast<int*>(buf);
  if (b < NCPAD / 256) {
    shi[t] = cnt[b * 256 + t];
    __syncthreads();
    for (int off = 128; off > 0; off >>= 1) {
      if (t < off) shi[t] += shi[t + off];
      __syncthreads();
    }
    if (t == 0) bsum[b] = shi[0];
  }
  grid.sync();

  // ================= P3: merged scan (block prefix + chunk scan) =========
  if (b < NCPAD / 256) {
    shi[t] = (t < b) ? bsum[t] : 0;   // t < b < 196 ensures valid read
    __syncthreads();
    for (int off = 128; off > 0; off >>= 1) {
      if (t < off) shi[t] += shi[t + off];
      __syncthreads();
    }
    if (t == 0) pre_s = shi[0];
    __syncthreads();
    int v = cnt[b * 256 + t];
    shi[t] = v;
    __syncthreads();
    for (int off = 1; off < 256; off <<= 1) {
      int u = (t >= off) ? shi[t - off] : 0;
      __syncthreads();
      shi[t] += u;
      __syncthreads();
    }
    cnt[b * 256 + t] = shi[t] - v + pre_s;   // exclusive global base
  }
  grid.sync();

  // ================= P4: place sorted {dst,src} records ==================
  for (int i = tid; i < NEDGE; i += gsz) {
    int d = dstE[i];
    int p = cnt[d] + (int)rankA[i];
    sdS[p] = ((unsigned long long)(unsigned)d << 32) | (unsigned)src[i];
  }
  grid.sync();

  // ================= P5: fused MLP + segmented max =======================
  const int lane = t & 63;
  const int w = t >> 6;
  const int l16 = lane & 15;
  const int quad = lane >> 4;

  for (int tile = b; tile < NTILES; tile += gridDim.x) {
    const int e0 = tile * TILE;

    // ---- Stage A-tile into buf (LDA stride): 128 edges x 96 k bf16
    {
      const int e = t >> 1, p = t & 1;
      const unsigned long long rec = sdS[e0 + e];
      const int s = (int)(rec & 0xffffffffu);
      const short8* xr = reinterpret_cast<const short8*>(xbf + (size_t)s * DF);
      for (int i = 0; i < 4; ++i)
        *reinterpret_cast<short8*>(&buf[e * LDA + p * 32 + i * 8]) = xr[p * 4 + i];
      short8 z = {0, 0, 0, 0, 0, 0, 0, 0};
      *reinterpret_cast<short8*>(&buf[e * LDA + 72 + p * 16]) = z;
      *reinterpret_cast<short8*>(&buf[e * LDA + 72 + p * 16 + 8]) = z;
    }
    if (t < TILE) {
      const unsigned long long rec = sdS[e0 + t];
      const int s = (int)(rec & 0xffffffffu);
      const int c = (int)(rec >> 32);
      dstLoc[t] = c;
      float dx = pos[(size_t)s * 3 + 0] - pos_c[(size_t)c * 3 + 0];
      float dy = pos[(size_t)s * 3 + 1] - pos_c[(size_t)c * 3 + 1];
      float dz = pos[(size_t)s * 3 + 2] - pos_c[(size_t)c * 3 + 2];
      short8 wv = {0, 0, 0, 0, 0, 0, 0, 0};
      wv[0] = (short)f2bf(dx); wv[1] = (short)f2bf(dy); wv[2] = (short)f2bf(dz);
      *reinterpret_cast<short8*>(&buf[t * LDA + 64]) = wv;
    }
    __syncthreads();

    // ---- GEMM1 A-fragments into registers, then buf is free for H1
    short8 a1[2][3];
    for (int mi = 0; mi < 2; ++mi) {
      int row = (2 * w + mi) * 16 + l16;
      for (int ks = 0; ks < 3; ++ks)
        a1[mi][ks] = *reinterpret_cast<const short8*>(&buf[row * LDA + ks * 32 + quad * 8]);
    }
    __syncthreads();

    // ---- GEMM1: [128 x 96] @ [96 x 128] -> relu -> H1 (bf16, LDH stride)
    for (int nt = 0; nt < 8; ++nt) {
      short8 bb[3];
      for (int ks = 0; ks < 3; ++ks)
        bb[ks] = *reinterpret_cast<const short8*>(W1f + ((size_t)(nt * 3 + ks) * 64 + lane) * 8);
      f32x4 acc0 = {0.f, 0.f, 0.f, 0.f}, acc1 = {0.f, 0.f, 0.f, 0.f};
      for (int ks = 0; ks < 3; ++ks) {
        acc0 = __builtin_amdgcn_mfma_f32_16x16x32_bf16(a1[0][ks], bb[ks], acc0, 0, 0, 0);
        acc1 = __builtin_amdgcn_mfma_f32_16x16x32_bf16(a1[1][ks], bb[ks], acc1, 0, 0, 0);
      }
      int n = nt * 16 + l16;
      float bias = b1[n];
      for (int r = 0; r < 4; ++r) {
        float v0 = acc0[r] + bias; v0 = v0 > 0.f ? v0 : 0.f;
        buf[((2 * w) * 16 + quad * 4 + r) * LDH + n] = f2bf(v0);
        float v1 = acc1[r] + bias; v1 = v1 > 0.f ? v1 : 0.f;
        buf[((2 * w + 1) * 16 + quad * 4 + r) * LDH + n] = f2bf(v1);
      }
    }
    __syncthreads();

    // ---- GEMM2 A-fragments into registers, then buf is free for Sf2
    short8 a2[2][4];
    for (int mi = 0; mi < 2; ++mi) {
      int row = (2 * w + mi) * 16 + l16;
      for (int ks = 0; ks < 4; ++ks)
        a2[mi][ks] = *reinterpret_cast<const short8*>(&buf[row * LDH + ks * 32 + quad * 8]);
    }
    __syncthreads();

    // Sf2 transposed: [col 0..63][edge 0..127], stride LDE floats
    float* Sf = reinterpret_cast<float*>(buf);
    const int col = t & 63;
    const int chunk = t >> 6;

    unsigned mask32;
    {
      int pred = 0;
      if (lane > 0 && lane < 32)
        pred = (dstLoc[chunk * 32 + lane] != dstLoc[chunk * 32 + lane - 1]) ? 1 : 0;
      mask32 = (unsigned)(__ballot(pred) & 0xffffffffull);
    }

    for (int half = 0; half < 2; ++half) {
      for (int ntl = 0; ntl < 4; ++ntl) {
        const int nt = half * 4 + ntl;
        short8 bb[4];
        for (int ks = 0; ks < 4; ++ks)
          bb[ks] = *reinterpret_cast<const short8*>(W2f + ((size_t)(nt * 4 + ks) * 64 + lane) * 8);
        f32x4 acc0 = {0.f, 0.f, 0.f, 0.f}, acc1 = {0.f, 0.f, 0.f, 0.f};
        for (int ks = 0; ks < 4; ++ks) {
          acc0 = __builtin_amdgcn_mfma_f32_16x16x32_bf16(a2[0][ks], bb[ks], acc0, 0, 0, 0);
          acc1 = __builtin_amdgcn_mfma_f32_16x16x32_bf16(a2[1][ks], bb[ks], acc1, 0, 0, 0);
        }
        const int nl = ntl * 16 + l16;
        const float bias = b2[half * 64 + nl];
        for (int r = 0; r < 4; ++r) { acc0[r] += bias; acc1[r] += bias; }
        *reinterpret_cast<f32x4*>(&Sf[nl * LDE + (2 * w) * 16 + quad * 4]) = acc0;
        *reinterpret_cast<f32x4*>(&Sf[nl * LDE + (2 * w + 1) * 16 + quad * 4]) = acc1;
      }
      __syncthreads();
      // segmented max over this wave's 32 sorted edges, vectorized 4-wide
      float running = -3.402823466e38f;
      const float* row = &Sf[col * LDE + chunk * 32];
      for (int g = 0; g < 8; ++g) {
        f32x4 v = *reinterpret_cast<const f32x4*>(row + 4 * g);
        unsigned bits = (mask32 >> (4 * g)) & 0xFu;
        if (bits == 0u) {
          running = fmaxf(running, fmaxf(fmaxf(v[0], v[1]), fmaxf(v[2], v[3])));
        } else {
          for (int j = 0; j < 4; ++j) {
            if ((bits >> j) & 1u) {
              int dprev = dstLoc[chunk * 32 + 4 * g + j - 1];
              atomicMax(&outU[(size_t)dprev * DOUT + half * 64 + col], encodeKey(running));
              running = -3.402823466e38f;
            }
            running = fmaxf(running, v[j]);
          }
        }
      }
      int dlast = dstLoc[chunk * 32 + 31];
      atomicMax(&outU[(size_t)dlast * DOUT + half * 64 + col], encodeKey(running));
      __syncthreads();
    }
  }
  grid.sync();

  // ================= P6: decode keys -> floats ===========================
  for (int i = tid; i < NCENT * DOUT / 4; i += gsz) {
    uint4 v = reinterpret_cast<uint4*>(outU)[i];
    float4 f;
    f.x = decodeKey(v.x);
    f.y = decodeKey(v.y);
    f.z = decodeKey(v.z);
    f.w = decodeKey(v.w);
    reinterpret_cast<float4*>(outU)[i] = f;
  }
}

extern "C" void kernel_launch(void* const* d_in, const int* in_sizes, int n_in,
                              void* d_out, int out_size, void* d_ws, size_t ws_size,
                              hipStream_t stream) {
  const float* x     = (const float*)d_in[0];
  // d_in[1] = x_c: only shape used by reference
  const float* pos   = (const float*)d_in[2];
  const float* pos_c = (const float*)d_in[3];
  const int*   src   = (const int*)d_in[4];
  const int*   dst   = (const int*)d_in[5];
  const float* W1    = (const float*)d_in[6];
  const float* b1    = (const float*)d_in[7];
  const float* W2    = (const float*)d_in[8];
  const float* b2    = (const float*)d_in[9];
  unsigned* outU = (unsigned*)d_out;

  // workspace layout (bytes)
  char* base = (char*)d_ws;
  unsigned short* W1f = (unsigned short*)base;                     // 24576
  unsigned short* W2f = (unsigned short*)(base + 24576);           // 32768 -> 57344
  int* bsum  = (int*)(base + 57344);                               // 1024  -> 58368 (pad to 65536)
  int* cnt   = (int*)(base + 65536);                               // 200704 -> 266240
  unsigned short* rank = (unsigned short*)(base + 266240);         // 3.2MB -> 3466240
  unsigned long long* sdS = (unsigned long long*)(base + 3466240); // 12.8MB -> 16266240
  unsigned short* xbf = (unsigned short*)(base + 16266240);        // 12.8MB -> 29066240
  // total ~= 27.7 MB

  int perCU = 0;
  if (hipOccupancyMaxActiveBlocksPerMultiprocessor(&perCU, k_all, 256, 0) != hipSuccess
      || perCU < 1)
    perCU = 1;
  int nblk = perCU * 256;          // 256 CUs on MI355X
  if (nblk > 1024) nblk = 1024;    // cap: all phases are grid-stride
  if (nblk < 256) nblk = 256;      // scan phases need >= 196 blocks

  void* args[] = {
    (void*)&x, (void*)&pos, (void*)&pos_c, (void*)&src, (void*)&dst,
    (void*)&W1, (void*)&b1, (void*)&W2, (void*)&b2, (void*)&outU,
    (void*)&xbf, (void*)&W1f, (void*)&W2f, (void*)&cnt, (void*)&rank,
    (void*)&bsum, (void*)&sdS
  };
  hipLaunchCooperativeKernel(k_all, dim3(nblk), dim3(256), args, 0, stream);
}